// Round 7
// baseline (14517.368 us; speedup 1.0000x reference)
//
#include <hip/hip_runtime.h>
#include <math.h>

#define NFEAT 128
#define NH 255
#define NP 256
#define NI 254
#define NBATCH 128
#define EPSQ 1e-4f
#define NITER 20
#define SIGMA 0.1f
#define BLOCK 512
#define KBCH 8
#define GBROW 320                       /* 256 data + 8x8 skew gaps */
#define KLSIZE 33408                    /* packed lower triangle + bank-despread gaps */
#define SMEM_FLOATS (KLSIZE + KBCH*GBROW + 16*256 + 64)
#define SMEM_BYTES (SMEM_FLOATS*4)

// packed lower-triangle index, rows padded to 4 floats, PLUS one float4 gap before
// every 8th row: base(8m) mod 32 = 20m+4 -> all 8 16B bank groups hit (was {0,16}).
__device__ __forceinline__ int IDX(int i, int j){
  int a = i >> 2, bb = i & 3;
  return 4*(a+1)*(2*a + bb) + 4*((i>>3)+1) + j;
}
// gb intra-row skew: element j stored at j + 8*(j/32); spreads tile-offsets over banks
#define MAPJ(x) ((x) + (((x)>>5)<<3))

__device__ __forceinline__ float clampf(float x, float m){
  return fminf(fmaxf(x, -m), m);      // also scrubs NaN -> -m
}

// ---------------- setup kernels ----------------
__global__ void k_setupQ(const float* __restrict__ L, float* __restrict__ Q){
  int i = blockIdx.x, j = threadIdx.x;
  float acc;
  if (i < NH && j < NH){
    int kmax = (i < j) ? i : j;
    acc = 0.0f;
    for (int k = 0; k <= kmax; ++k) acc = fmaf(L[i*NH + k], L[j*NH + k], acc);
    if (i == j) acc += EPSQ;
  } else {
    acc = (i == j) ? 1.0f : 0.0f;   // padded row/col 255 = e255
  }
  Q[i*NP + j] = acc;
}
__global__ void k_setupP(const float* __restrict__ x, const float* __restrict__ W,
                         const float* __restrict__ bias, float* __restrict__ P){
  int b = blockIdx.x, j = threadIdx.x;
  float acc = 0.0f;
  if (j < NH){
    acc = bias[j];
    for (int f = 0; f < NFEAT; ++f) acc = fmaf(x[b*NFEAT + f], W[j*NFEAT + f], acc);
  }
  P[b*NP + j] = acc;
}
__global__ void k_setupH(const float* __restrict__ G, const float* __restrict__ z0,
                         const float* __restrict__ s0, float* __restrict__ H){
  int k = threadIdx.x;
  float acc = 0.0f;
  if (k < NI){
    acc = s0[k];
    for (int i = 0; i < NH; ++i) acc = fmaf(G[k*NH + i], z0[i], acc);
  }
  H[k] = acc;
}
__global__ void k_setupGt(const float* __restrict__ G, float* __restrict__ Gt){
  int i = blockIdx.x, k = threadIdx.x;
  float v = 0.0f;
  if (i < NH && k < NI) v = G[k*NH + i];
  Gt[i*NP + k] = v;
}

// ---------------- main QP kernel: one block per batch row ----------------
__global__ void
__attribute__((amdgpu_flat_work_group_size(512, 512), amdgpu_waves_per_eu(2, 2)))
qp_kernel(
    const float* __restrict__ Qg, const float* __restrict__ G,
    const float* __restrict__ Gt,
    const float* __restrict__ Pg, const float* __restrict__ Hg,
    float* __restrict__ out)
{
  extern __shared__ float sm[];
  float* Kl   = sm;                 // KLSIZE
  float* gb   = Kl + KLSIZE;        // KBCH*GBROW
  float* zv   = gb + KBCH*GBROW;
  float* sv   = zv + NP;
  float* lv   = sv + NP;
  float* psh  = lv + NP;
  float* hsh  = psh + NP;
  float* r1   = hsh + NP;
  float* r2   = r1 + NP;
  float* r3   = r2 + NP;
  float* dd   = r3 + NP;
  float* wwv  = dd + NP;
  float* dsv  = wwv + NP;
  float* dlv  = dsv + NP;
  float* yv   = dlv + NP;
  float* invd = yv + NP;
  float* dscv = invd + NP;
  float* qdg  = dscv + NP;
  float* misc = qdg + NP;           // 64

  const int tid  = threadIdx.x;
  const int lane = tid & 63;
  const int wv   = tid >> 6;
  const int b    = blockIdx.x;

  // zero ALL of LDS: gaps/padding stay 0 forever -> float4 over-reads benign
  for (int i = tid; i < SMEM_FLOATS; i += BLOCK) sm[i] = 0.0f;
  __syncthreads();

  // ---- static mappings ----
  int ktr = 0, ktc = 0;
  if (tid < 496){
    int t = tid;
    int r = (int)((sqrtf(8.0f*(float)t + 1.0f) + 1.0f)*0.5f);
    while (r*(r-1)/2 > t) --r;
    while ((r+1)*r/2 <= t) ++r;
    ktr = r; ktc = t - r*(r-1)/2;
  }
  const int i0 = ktr*8, j0k = ktc*8;

  int dI[3], dJ[3];
  #pragma unroll
  for (int q = 0; q < 3; ++q){
    int e = tid + 512*q;
    if (e < 1152){
      int dt = e/36, e36 = e - dt*36;
      int r = (int)((sqrtf(8.0f*(float)e36 + 1.0f) - 1.0f)*0.5f);
      while (r*(r+1)/2 > e36) --r;
      while ((r+1)*(r+2)/2 <= e36) ++r;
      int c = e36 - r*(r+1)/2;
      dI[q] = dt*8 + r; dJ[q] = dt*8 + c;
    } else { dI[q] = -1; dJ[q] = 0; }
  }

  // ---- init state ----
  for (int i = tid; i < NP; i += BLOCK){
    zv[i] = 0.0f;
    sv[i] = 1.0f;
    lv[i] = (i < NI) ? 1.0f : 0.0f;
    psh[i] = Pg[b*NP + i];
    hsh[i] = Hg[i];
    qdg[i] = Qg[i*NP + i];
  }
  __syncthreads();

  for (int it = 0; it < NITER; ++it){
    // ---- A (fused): r1 = Q z + Gt lam + p  (coalesced wave-per-row) ----
    {
      int ib0 = wv*32;
      float z0l = zv[lane], z1l = zv[lane+64], z2l = zv[lane+128], z3l = zv[lane+192];
      float l0 = lv[lane], l1 = lv[lane+64], l2 = lv[lane+128], l3 = lv[lane+192];
      for (int i = ib0; i < ib0 + 32; i += 2){
        const float* q0 = Qg + i*NP;  const float* q1 = q0 + NP;
        const float* g0 = Gt + i*NP;  const float* g1 = g0 + NP;
        float v0 = q0[lane]*z0l + q0[lane+64]*z1l + q0[lane+128]*z2l + q0[lane+192]*z3l
                 + g0[lane]*l0  + g0[lane+64]*l1  + g0[lane+128]*l2  + g0[lane+192]*l3;
        float v1 = q1[lane]*z0l + q1[lane+64]*z1l + q1[lane+128]*z2l + q1[lane+192]*z3l
                 + g1[lane]*l0  + g1[lane+64]*l1  + g1[lane+128]*l2  + g1[lane+192]*l3;
        #pragma unroll
        for (int m = 32; m >= 1; m >>= 1){ v0 += __shfl_xor(v0, m, 64); v1 += __shfl_xor(v1, m, 64); }
        if (lane == 0){ r1[i] = v0 + psh[i]; r1[i+1] = v1 + psh[i+1]; }
      }
    }
    // ---- B: r2 = G z + s - h (wave-per-row over G) ----
    {
      int kb = wv*32, ke = min(kb + 32, NI);
      float z0l = zv[lane], z1l = zv[lane+64], z2l = zv[lane+128];
      float z3l = (lane < 63) ? zv[lane+192] : 0.0f;
      for (int k = kb; k < ke; k += 2){
        const float* g0 = G + k*NH;
        const float* g1 = g0 + NH;
        float a3 = (lane < 63) ? g0[lane+192] : 0.0f;
        float b3 = (lane < 63) ? g1[lane+192] : 0.0f;
        float v0 = g0[lane]*z0l + g0[lane+64]*z1l + g0[lane+128]*z2l + a3*z3l;
        float v1 = g1[lane]*z0l + g1[lane+64]*z1l + g1[lane+128]*z2l + b3*z3l;
        #pragma unroll
        for (int m = 32; m >= 1; m >>= 1){ v0 += __shfl_xor(v0, m, 64); v1 += __shfl_xor(v1, m, 64); }
        if (lane == 0){
          r2[k]   = v0 + sv[k]   - hsh[k];
          r2[k+1] = v1 + sv[k+1] - hsh[k+1];
        }
      }
    }
    __syncthreads();
    // ---- C: mu, r3, d, w (2 barriers; every thread sums the 8 partials) ----
    {
      float sl = (tid < NI) ? sv[tid]*lv[tid] : 0.0f;
      #pragma unroll
      for (int m = 32; m >= 1; m >>= 1) sl += __shfl_xor(sl, m, 64);
      if (lane == 0) misc[wv] = sl;
    }
    __syncthreads();
    {
      float t = 0.0f;
      #pragma unroll
      for (int q = 0; q < 8; ++q) t += misc[q];
      float mu = SIGMA * (t * (1.0f/(float)NI));
      if (tid < NI){
        float sk = sv[tid], lk = lv[tid];
        float skg = fmaxf(sk, 1e-30f);
        float r3k = sk*lk - mu;
        r3[tid] = r3k;
        dd[tid] = fminf(lk/skg, 1e24f);
        wwv[tid] = clampf((lk*r2[tid] - r3k)/skg, 1e30f);
      }
    }
    __syncthreads();
    // ---- D (fused D0+D): dscv = rsqrt(diag), yv = scaled rhs (one Gt pass) ----
    {
      int ib0 = wv*32;
      float d0 = dd[lane], d1 = dd[lane+64], d2 = dd[lane+128], d3 = dd[lane+192];
      float w0 = wwv[lane], w1 = wwv[lane+64], w2 = wwv[lane+128], w3 = wwv[lane+192];
      for (int i = ib0; i < ib0 + 32; i += 2){
        const float* g0 = Gt + i*NP;
        const float* g1 = g0 + NP;
        float a0 = g0[lane], a1 = g0[lane+64], a2 = g0[lane+128], a3 = g0[lane+192];
        float b0 = g1[lane], b1 = g1[lane+64], b2 = g1[lane+128], b3 = g1[lane+192];
        float u0 = a0*a0*d0 + a1*a1*d1 + a2*a2*d2 + a3*a3*d3;   // G^T D G diag part
        float u1 = b0*b0*d0 + b1*b1*d1 + b2*b2*d2 + b3*b3*d3;
        float v0 = a0*w0 + a1*w1 + a2*w2 + a3*w3;               // w @ G
        float v1 = b0*w0 + b1*w1 + b2*w2 + b3*w3;
        #pragma unroll
        for (int m = 32; m >= 1; m >>= 1){
          u0 += __shfl_xor(u0, m, 64); u1 += __shfl_xor(u1, m, 64);
          v0 += __shfl_xor(v0, m, 64); v1 += __shfl_xor(v1, m, 64);
        }
        if (lane == 0){
          float s0_ = rsqrtf(fmaxf(qdg[i]   + u0, 1e-12f));
          float s1_ = rsqrtf(fmaxf(qdg[i+1] + u1, 1e-12f));
          dscv[i]   = s0_;  yv[i]   = -(r1[i]   + v0) * s0_;
          dscv[i+1] = s1_;  yv[i+1] = -(r1[i+1] + v1) * s1_;
        }
      }
    }
    __syncthreads();

    // ---- E: K~ = S(Q + G^T D G)S, packed lower triangle in LDS ----
    // two passes of 4 rows x 8 cols (accT[32] live -> no spill at 128 VGPR)
    float accD[3];
    #pragma unroll
    for (int q = 0; q < 3; ++q) accD[q] = (dI[q] >= 0) ? Qg[dI[q]*NP + dJ[q]] : 0.0f;

    #pragma unroll 1
    for (int p = 0; p < 2; ++p){
      const int ri0 = i0 + 4*p;
      float accT[32];
      if (tid < 496){
        #pragma unroll
        for (int r = 0; r < 4; ++r){
          float4 qa = *reinterpret_cast<const float4*>(&Qg[(ri0+r)*NP + j0k]);
          float4 qb = *reinterpret_cast<const float4*>(&Qg[(ri0+r)*NP + j0k + 4]);
          accT[r*8+0]=qa.x; accT[r*8+1]=qa.y; accT[r*8+2]=qa.z; accT[r*8+3]=qa.w;
          accT[r*8+4]=qb.x; accT[r*8+5]=qb.y; accT[r*8+6]=qb.z; accT[r*8+7]=qb.w;
        }
      }
      for (int c0 = 0; c0 < NP; c0 += KBCH){
        __syncthreads();
        { // stage sqrt(d[k]) * G[k][:] rows c0..c0+7, skewed (zero-padded)
          int base = tid*4;
          int kk = base >> 8;
          int j  = base & 255;
          int krow = c0 + kk;
          float4 v; v.x = v.y = v.z = v.w = 0.0f;
          if (krow < NI){
            float sd = sqrtf(dd[krow]);
            const float* gr = G + krow*NH + j;
            v.x = gr[0]*sd;
            v.y = gr[1]*sd;
            v.z = gr[2]*sd;
            v.w = (j + 3 < NH) ? gr[3]*sd : 0.0f;
          }
          *reinterpret_cast<float4*>(&gb[kk*GBROW + MAPJ(j)]) = v;
        }
        __syncthreads();
        #pragma unroll
        for (int kk = 0; kk < KBCH; ++kk){
          const float* gr = gb + kk*GBROW;
          if (p == 0){
            #pragma unroll
            for (int q = 0; q < 3; ++q)
              if (dI[q] >= 0) accD[q] = fmaf(gr[MAPJ(dI[q])], gr[MAPJ(dJ[q])], accD[q]);
          }
          if (tid < 496){
            float4 a0 = *reinterpret_cast<const float4*>(&gr[MAPJ(ri0)]);
            float4 b0 = *reinterpret_cast<const float4*>(&gr[MAPJ(j0k)]);
            float4 b1 = *reinterpret_cast<const float4*>(&gr[MAPJ(j0k) + 4]);
            float gi[4] = {a0.x,a0.y,a0.z,a0.w};
            float gj[8] = {b0.x,b0.y,b0.z,b0.w,b1.x,b1.y,b1.z,b1.w};
            #pragma unroll
            for (int r = 0; r < 4; ++r){
              #pragma unroll
              for (int c = 0; c < 8; ++c) accT[r*8+c] = fmaf(gi[r], gj[c], accT[r*8+c]);
            }
          }
        }
      }
      if (tid < 496){
        #pragma unroll
        for (int r = 0; r < 4; ++r){
          float sr = dscv[ri0 + r];
          int rb = IDX(ri0+r, j0k);
          float4 v0, v1;
          v0.x=accT[r*8+0]*sr*dscv[j0k+0]; v0.y=accT[r*8+1]*sr*dscv[j0k+1];
          v0.z=accT[r*8+2]*sr*dscv[j0k+2]; v0.w=accT[r*8+3]*sr*dscv[j0k+3];
          v1.x=accT[r*8+4]*sr*dscv[j0k+4]; v1.y=accT[r*8+5]*sr*dscv[j0k+5];
          v1.z=accT[r*8+6]*sr*dscv[j0k+6]; v1.w=accT[r*8+7]*sr*dscv[j0k+7];
          *reinterpret_cast<float4*>(&Kl[rb])   = v0;
          *reinterpret_cast<float4*>(&Kl[rb+4]) = v1;
        }
      }
      if (p == 0){
        #pragma unroll
        for (int q = 0; q < 3; ++q)
          if (dI[q] >= 0) Kl[IDX(dI[q], dJ[q])] = accD[q]*dscv[dI[q]]*dscv[dJ[q]];
      }
    }
    __syncthreads();

    // ---- F: blocked Cholesky (NB=16) on K~ ----
    for (int pan = 0; pan < 16; ++pan){
      int j0 = pan*16;
      if (tid < 64){
        int r = lane & 15;
        int rb = IDX(j0 + r, j0);
        float a[16];
        #pragma unroll
        for (int qq = 0; qq < 4; ++qq){
          float4 v = *reinterpret_cast<const float4*>(&Kl[rb + 4*qq]);
          a[4*qq+0]=v.x; a[4*qq+1]=v.y; a[4*qq+2]=v.z; a[4*qq+3]=v.w;
        }
        #pragma unroll
        for (int j = 0; j < 16; ++j){
          float dj = __shfl(a[j], j);
          dj = (dj > 1e-8f) ? dj : 1e-8f;
          float piv = sqrtf(dj);
          float inv = 1.0f/piv;
          float lrj = clampf(a[j]*inv, 4.0f);
          a[j] = (r == j) ? piv : lrj;
          if (lane == j) invd[j0+j] = inv;
          #pragma unroll
          for (int c = j+1; c < 16; ++c){
            float lcj = __shfl(a[j], c);
            a[c] = fmaf(-a[j], lcj, a[c]);
          }
        }
        if (lane < 16){
          #pragma unroll
          for (int c = 0; c < 16; ++c)
            if (c <= r) Kl[rb + c] = a[c];
        }
      }
      __syncthreads();
      int t0p = j0 + 16;
      if (t0p < NP){
        if (tid < NP - t0p){
          int i = t0p + tid;
          int rb = IDX(i, j0);
          float a[16];
          #pragma unroll
          for (int qq = 0; qq < 4; ++qq){
            float4 v = *reinterpret_cast<const float4*>(&Kl[rb + 4*qq]);
            a[4*qq+0]=v.x; a[4*qq+1]=v.y; a[4*qq+2]=v.z; a[4*qq+3]=v.w;
          }
          #pragma unroll
          for (int c = 0; c < 16; ++c){
            float v = a[c];
            int cb = IDX(j0+c, j0);
            #pragma unroll
            for (int k = 0; k < 16; ++k){ if (k < c) v -= a[k]*Kl[cb + k]; }
            a[c] = clampf(v * invd[j0+c], 4.0f);
          }
          #pragma unroll
          for (int qq = 0; qq < 4; ++qq){
            float4 v; v.x=a[4*qq]; v.y=a[4*qq+1]; v.z=a[4*qq+2]; v.w=a[4*qq+3];
            *reinterpret_cast<float4*>(&Kl[rb + 4*qq]) = v;
          }
        }
        __syncthreads();
        int nt = NP - t0p;
        int ntr = nt >> 3;
        int offt = ntr*(ntr-1)/2;
        for (int tt = tid; tt < offt; tt += BLOCK){
          int r = (int)((sqrtf(8.0f*(float)tt + 1.0f) + 1.0f)*0.5f);
          while (r*(r-1)/2 > tt) --r;
          while ((r+1)*r/2 <= tt) ++r;
          int c = tt - r*(r-1)/2;
          int ri = t0p + r*8, rj = t0p + c*8;
          float acc[64];
          #pragma unroll
          for (int q = 0; q < 64; ++q) acc[q] = 0.0f;
          #pragma unroll
          for (int ks = 0; ks < 4; ++ks){
            float4 Lc[8];
            #pragma unroll
            for (int q = 0; q < 8; ++q)
              Lc[q] = *reinterpret_cast<const float4*>(&Kl[IDX(rj+q, j0) + 4*ks]);
            #pragma unroll
            for (int rr = 0; rr < 8; ++rr){
              float4 Li = *reinterpret_cast<const float4*>(&Kl[IDX(ri+rr, j0) + 4*ks]);
              #pragma unroll
              for (int cc = 0; cc < 8; ++cc){
                float v = acc[rr*8+cc];
                v = fmaf(Li.x, Lc[cc].x, v);
                v = fmaf(Li.y, Lc[cc].y, v);
                v = fmaf(Li.z, Lc[cc].z, v);
                v = fmaf(Li.w, Lc[cc].w, v);
                acc[rr*8+cc] = v;
              }
            }
          }
          #pragma unroll
          for (int rr = 0; rr < 8; ++rr){
            int rb2 = IDX(ri+rr, rj);
            float4 v0 = *reinterpret_cast<const float4*>(&Kl[rb2]);
            float4 v1 = *reinterpret_cast<const float4*>(&Kl[rb2+4]);
            v0.x -= acc[rr*8+0]; v0.y -= acc[rr*8+1]; v0.z -= acc[rr*8+2]; v0.w -= acc[rr*8+3];
            v1.x -= acc[rr*8+4]; v1.y -= acc[rr*8+5]; v1.z -= acc[rr*8+6]; v1.w -= acc[rr*8+7];
            *reinterpret_cast<float4*>(&Kl[rb2])   = v0;
            *reinterpret_cast<float4*>(&Kl[rb2+4]) = v1;
          }
        }
        int nde = ntr*36;
        for (int e = tid; e < nde; e += BLOCK){
          int dt = e/36, e36 = e - dt*36;
          int rr = (int)((sqrtf(8.0f*(float)e36 + 1.0f) - 1.0f)*0.5f);
          while (rr*(rr+1)/2 > e36) --rr;
          while ((rr+1)*(rr+2)/2 <= e36) ++rr;
          int cc = e36 - rr*(rr+1)/2;
          int i  = t0p + dt*8 + rr;
          int jc = t0p + dt*8 + cc;
          int ri2 = IDX(i, j0), rj2 = IDX(jc, j0);
          float acc = 0.0f;
          #pragma unroll
          for (int ks = 0; ks < 4; ++ks){
            float4 av = *reinterpret_cast<const float4*>(&Kl[ri2 + 4*ks]);
            float4 bv = *reinterpret_cast<const float4*>(&Kl[rj2 + 4*ks]);
            acc = fmaf(av.x, bv.x, acc); acc = fmaf(av.y, bv.y, acc);
            acc = fmaf(av.z, bv.z, acc); acc = fmaf(av.w, bv.w, acc);
          }
          Kl[IDX(i, jc)] -= acc;
        }
      }
      __syncthreads();
    }

    // ---- G: forward solve L y = rhs~ ----
    for (int pan = 0; pan < 16; ++pan){
      int j0 = pan*16;
      if (tid < 64){
        int r = lane & 15;
        int rb = IDX(j0 + r, j0);
        float l[16];
        #pragma unroll
        for (int qq = 0; qq < 4; ++qq){
          float4 v = *reinterpret_cast<const float4*>(&Kl[rb + 4*qq]);
          l[4*qq+0]=v.x; l[4*qq+1]=v.y; l[4*qq+2]=v.z; l[4*qq+3]=v.w;
        }
        float y   = yv[j0 + r];
        float miv = invd[j0 + r];
        #pragma unroll
        for (int j = 0; j < 16; ++j){
          float t = __shfl(y, j) * __shfl(miv, j);
          if (r == j) y = t;
          else if (r > j) y = fmaf(-l[j], t, y);
        }
        if (lane < 16) yv[j0 + r] = y;
      }
      __syncthreads();
      int t0p = j0 + 16;
      if (t0p < NP && tid < NP - t0p){
        int i = t0p + tid;
        int rb = IDX(i, j0);
        float acc = yv[i];
        #pragma unroll
        for (int k = 0; k < 16; ++k) acc -= Kl[rb + k]*yv[j0+k];
        yv[i] = acc;
      }
      __syncthreads();
    }
    // ---- H: back solve L^T dz~ = y ----
    for (int pan = 15; pan >= 0; --pan){
      int j0 = pan*16;
      if (tid < 64){
        int r = lane & 15;
        float col[16];
        #pragma unroll
        for (int j = 0; j < 16; ++j) col[j] = Kl[IDX(j0 + j, j0) + r];
        float y   = yv[j0 + r];
        float miv = invd[j0 + r];
        #pragma unroll
        for (int j = 15; j >= 0; --j){
          float t = __shfl(y, j) * __shfl(miv, j);
          if (r == j) y = t;
          else if (r < j) y = fmaf(-col[j], t, y);
        }
        if (lane < 16) yv[j0 + r] = y;
      }
      __syncthreads();
      if (j0 > 0 && tid < j0){
        int i = tid;
        float acc = yv[i];
        #pragma unroll
        for (int k = 0; k < 16; ++k) acc -= Kl[IDX(j0+k, i)]*yv[j0+k];
        yv[i] = acc;
      }
      __syncthreads();
    }
    // ---- unscale: dz = S dz~ ----
    if (tid < NP) yv[tid] = clampf(yv[tid]*dscv[tid], 1e30f);
    __syncthreads();

    // ---- I: ds = -r2 - dz @ G^T (wave-per-row over G) ----
    {
      int kb = wv*32, ke = min(kb + 32, NI);
      float z0l = yv[lane], z1l = yv[lane+64], z2l = yv[lane+128];
      float z3l = (lane < 63) ? yv[lane+192] : 0.0f;
      for (int k = kb; k < ke; k += 2){
        const float* g0 = G + k*NH;
        const float* g1 = g0 + NH;
        float a3 = (lane < 63) ? g0[lane+192] : 0.0f;
        float b3 = (lane < 63) ? g1[lane+192] : 0.0f;
        float v0 = g0[lane]*z0l + g0[lane+64]*z1l + g0[lane+128]*z2l + a3*z3l;
        float v1 = g1[lane]*z0l + g1[lane+64]*z1l + g1[lane+128]*z2l + b3*z3l;
        #pragma unroll
        for (int m = 32; m >= 1; m >>= 1){ v0 += __shfl_xor(v0, m, 64); v1 += __shfl_xor(v1, m, 64); }
        if (lane == 0){
          dsv[k]   = clampf(-r2[k]   - v0, 1e30f);
          dsv[k+1] = clampf(-r2[k+1] - v1, 1e30f);
        }
      }
    }
    __syncthreads();
    // ---- J: dlam, alpha (2 barriers) ----
    float loc = 1e10f;
    if (tid < NI){
      float dsk = dsv[tid];
      float skg = fmaxf(sv[tid], 1e-30f);
      float dlk = clampf((-r3[tid] - lv[tid]*dsk)/skg, 1e30f);
      dlv[tid] = dlk;
      if (dsk < 0.0f) loc = fminf(loc, -sv[tid]/dsk);
      if (dlk < 0.0f) loc = fminf(loc, -lv[tid]/dlk);
    }
    #pragma unroll
    for (int m = 32; m >= 1; m >>= 1) loc = fminf(loc, __shfl_xor(loc, m, 64));
    if (lane == 0) misc[wv] = loc;
    __syncthreads();
    {
      float mn = 1e10f;
      #pragma unroll
      for (int q = 0; q < 8; ++q) mn = fminf(mn, misc[q]);
      float alpha = fminf(1.0f, 0.99f*mn);
      if (tid < NP) zv[tid] += alpha*yv[tid];
      if (tid < NI){
        sv[tid] += alpha*dsv[tid];
        lv[tid] += alpha*dlv[tid];
      }
    }
    __syncthreads();
  }

  if (tid < NFEAT) out[b*NFEAT + tid] = zv[tid];
}

extern "C" void kernel_launch(void* const* d_in, const int* in_sizes, int n_in,
                              void* d_out, int out_size, void* d_ws, size_t ws_size,
                              hipStream_t stream)
{
  const float* x    = (const float*)d_in[0];
  const float* W    = (const float*)d_in[1];
  const float* bias = (const float*)d_in[2];
  const float* L    = (const float*)d_in[3];
  const float* G    = (const float*)d_in[4];
  const float* z0   = (const float*)d_in[5];
  const float* s0   = (const float*)d_in[6];
  float* out = (float*)d_out;

  float* ws = (float*)d_ws;
  float* Qg = ws;               // 65536 floats
  float* Pg = Qg + 65536;       // 32768
  float* Hg = Pg + 32768;       // 256
  float* Gt = Hg + 256;         // 65536

  hipLaunchKernelGGL(k_setupQ,  dim3(NP),     dim3(NP), 0, stream, L, Qg);
  hipLaunchKernelGGL(k_setupP,  dim3(NBATCH), dim3(NP), 0, stream, x, W, bias, Pg);
  hipLaunchKernelGGL(k_setupH,  dim3(1),      dim3(NP), 0, stream, G, z0, s0, Hg);
  hipLaunchKernelGGL(k_setupGt, dim3(NP),     dim3(NP), 0, stream, G, Gt);

  hipFuncSetAttribute(reinterpret_cast<const void*>(qp_kernel),
                      hipFuncAttributeMaxDynamicSharedMemorySize, SMEM_BYTES);
  hipLaunchKernelGGL(qp_kernel, dim3(NBATCH), dim3(BLOCK), SMEM_BYTES, stream,
                     Qg, G, Gt, Pg, Hg, out);
}